// Round 1
// baseline (53.373 us; speedup 1.0000x reference)
//
#include <hip/hip_runtime.h>

// Problem constants (from reference)
#define KH 3
#define KW 3
#define IN_CH 64
#define OUT_CH 256
#define NUM_NODES 7
#define NUM_LEAVES 8
#define NB 16
#define NH 48
#define NW 48
#define NPIX (NH * NW)          // 2304
#define PATCH_LEN (IN_CH * KH * KW)

// GATE_COEFF[16][4]
__constant__ float c_gate[16 * 4] = {
    0.f, 0.f, 0.f, 0.f,
    0.f, 0.f, 0.f, 1.f,
    0.f, 1.f, 0.f, -1.f,
    0.f, 1.f, 0.f, 0.f,
    0.f, 0.f, 1.f, -1.f,
    0.f, 0.f, 1.f, 0.f,
    0.f, 1.f, 1.f, -2.f,
    0.f, 1.f, 1.f, -1.f,
    1.f, -1.f, -1.f, 1.f,
    1.f, -1.f, -1.f, 2.f,
    1.f, 0.f, -1.f, 0.f,
    1.f, 0.f, -1.f, 1.f,
    1.f, -1.f, 0.f, 0.f,
    1.f, -1.f, 0.f, 1.f,
    1.f, 0.f, 0.f, -1.f,
    1.f, 0.f, 0.f, 0.f
};

// Precompute w[o][n][4] = softmax(logits[o,n,:]) @ GATE_COEFF  (256*7 pairs)
__global__ __launch_bounds__(256) void precompute_w_kernel(
    const float* __restrict__ logits, float* __restrict__ w)
{
    int t = blockIdx.x * 256 + threadIdx.x;
    if (t >= OUT_CH * NUM_NODES) return;
    const float* lg = logits + (size_t)t * 16;

    float m = lg[0];
#pragma unroll
    for (int g = 1; g < 16; ++g) m = fmaxf(m, lg[g]);

    float e[16];
    float s = 0.f;
#pragma unroll
    for (int g = 0; g < 16; ++g) { e[g] = expf(lg[g] - m); s += e[g]; }
    float inv = 1.f / s;

    float w0 = 0.f, w1 = 0.f, w2 = 0.f, w3 = 0.f;
#pragma unroll
    for (int g = 0; g < 16; ++g) {
        float p = e[g] * inv;
        w0 += p * c_gate[g * 4 + 0];
        w1 += p * c_gate[g * 4 + 1];
        w2 += p * c_gate[g * 4 + 2];
        w3 += p * c_gate[g * 4 + 3];
    }
    reinterpret_cast<float4*>(w)[t] = make_float4(w0, w1, w2, w3);
}

// Main kernel: one thread per output element.
// grid = (NPIX/256, OUT_CH, NB), block = 256.
// All threads in a block share the same o -> leaf indices & weights are
// wave-uniform (scalar loads); gathers are coalesced along pw.
__global__ __launch_bounds__(256) void ltc_kernel(
    const float* __restrict__ x,        // [B][IN_CH][H][W]
    const int*   __restrict__ leaf_idx, // [OUT_CH][8]
    const float* __restrict__ w,        // [OUT_CH][7][4]
    float*       __restrict__ out)      // [B][OUT_CH][H][W]
{
    const int p  = blockIdx.x * 256 + threadIdx.x;   // pixel 0..2303
    const int o  = blockIdx.y;
    const int b  = blockIdx.z;
    const int ph = p / NW;
    const int pw = p - ph * NW;

    const float* xb = x + (size_t)b * IN_CH * NPIX;

    float v[NUM_LEAVES];
#pragma unroll
    for (int l = 0; l < NUM_LEAVES; ++l) {
        int idx = leaf_idx[o * NUM_LEAVES + l];   // uniform per block
        int c  = idx / 9;
        int k  = idx - c * 9;
        int di = k / 3 - 1;
        int dj = k - (k / 3) * 3 - 1;
        int r  = ph + di;
        int cc = pw + dj;
        bool ok = ((unsigned)r < NH) && ((unsigned)cc < NW);
        v[l] = ok ? xb[((size_t)c * NH + r) * NW + cc] : 0.f;
    }

    const float* wo = w + (size_t)o * NUM_NODES * 4;

    float t[4];
#pragma unroll
    for (int n = 0; n < 4; ++n) {
        float a  = v[2 * n];
        float bb = v[2 * n + 1];
        t[n] = wo[n * 4 + 0] + wo[n * 4 + 1] * a + wo[n * 4 + 2] * bb
             + wo[n * 4 + 3] * (a * bb);
    }

    float u[2];
#pragma unroll
    for (int mm = 0; mm < 2; ++mm) {
        float a  = t[2 * mm];
        float bb = t[2 * mm + 1];
        const float* wn = wo + (4 + mm) * 4;
        u[mm] = wn[0] + wn[1] * a + wn[2] * bb + wn[3] * (a * bb);
    }

    const float* wn = wo + 6 * 4;
    float y = wn[0] + wn[1] * u[0] + wn[2] * u[1] + wn[3] * (u[0] * u[1]);

    out[((size_t)(b * OUT_CH + o)) * NPIX + p] = y;
}

extern "C" void kernel_launch(void* const* d_in, const int* in_sizes, int n_in,
                              void* d_out, int out_size, void* d_ws, size_t ws_size,
                              hipStream_t stream) {
    const float* x        = (const float*)d_in[0];
    const float* logits   = (const float*)d_in[1];
    const int*   leaf_idx = (const int*)d_in[2];
    float*       out      = (float*)d_out;
    float*       w        = (float*)d_ws;   // 256*7*4 floats = 28672 B

    // 1) node weights
    precompute_w_kernel<<<(OUT_CH * NUM_NODES + 255) / 256, 256, 0, stream>>>(logits, w);

    // 2) main compute
    dim3 grid(NPIX / 256, OUT_CH, NB);
    ltc_kernel<<<grid, 256, 0, stream>>>(x, leaf_idx, w, out);
}

// Round 2
// 33.784 us; speedup vs baseline: 1.5798x; 1.5798x over previous
//
#include <hip/hip_runtime.h>

#define KH 3
#define KW 3
#define IN_CH 64
#define OUT_CH 256
#define NUM_NODES 7
#define NUM_LEAVES 8
#define NB 16
#define NH 48
#define NW 48
#define NPIX (NH * NW)            // 2304
#define PH 50
#define PW 50
#define PPIX (PH * PW)            // 2500
#define NPLANES (NB * IN_CH)      // 1024
#define PAD_ELEMS (NPLANES * PPIX)        // 2,560,000
#define PAD_BLOCKS ((PAD_ELEMS + 255) / 256)   // 10000
#define W_BLOCKS ((OUT_CH * NUM_NODES + 255) / 256) // 7

__constant__ float c_gate[16 * 4] = {
    0.f, 0.f, 0.f, 0.f,
    0.f, 0.f, 0.f, 1.f,
    0.f, 1.f, 0.f, -1.f,
    0.f, 1.f, 0.f, 0.f,
    0.f, 0.f, 1.f, -1.f,
    0.f, 0.f, 1.f, 0.f,
    0.f, 1.f, 1.f, -2.f,
    0.f, 1.f, 1.f, -1.f,
    1.f, -1.f, -1.f, 1.f,
    1.f, -1.f, -1.f, 2.f,
    1.f, 0.f, -1.f, 0.f,
    1.f, 0.f, -1.f, 1.f,
    1.f, -1.f, 0.f, 0.f,
    1.f, -1.f, 0.f, 1.f,
    1.f, 0.f, 0.f, -1.f,
    1.f, 0.f, 0.f, 0.f
};

// Fused prep: blocks [0, PAD_BLOCKS) zero-pad x into xp[B][64][50][50];
// blocks [PAD_BLOCKS, PAD_BLOCKS+W_BLOCKS) compute node weights
// w[o][n][4] = softmax(logits[o,n,:]) @ GATE_COEFF.
__global__ __launch_bounds__(256) void prep_kernel(
    const float* __restrict__ x,
    const float* __restrict__ logits,
    float* __restrict__ xp,
    float* __restrict__ w)
{
    if (blockIdx.x < PAD_BLOCKS) {
        int e = blockIdx.x * 256 + threadIdx.x;
        if (e >= PAD_ELEMS) return;
        int plane = e / PPIX;                 // b*64 + c
        int rc = e - plane * PPIX;
        int r = rc / PW;
        int c = rc - r * PW;
        float val = 0.f;
        if (r >= 1 && r <= NH && c >= 1 && c <= NW)
            val = x[(size_t)plane * NPIX + (r - 1) * NW + (c - 1)];
        xp[e] = val;
    } else {
        int t = (blockIdx.x - PAD_BLOCKS) * 256 + threadIdx.x;
        if (t >= OUT_CH * NUM_NODES) return;
        const float* lg = logits + (size_t)t * 16;

        float m = lg[0];
#pragma unroll
        for (int g = 1; g < 16; ++g) m = fmaxf(m, lg[g]);
        float e16[16];
        float s = 0.f;
#pragma unroll
        for (int g = 0; g < 16; ++g) { e16[g] = expf(lg[g] - m); s += e16[g]; }
        float inv = 1.f / s;

        float w0 = 0.f, w1 = 0.f, w2 = 0.f, w3 = 0.f;
#pragma unroll
        for (int g = 0; g < 16; ++g) {
            float p = e16[g] * inv;
            w0 += p * c_gate[g * 4 + 0];
            w1 += p * c_gate[g * 4 + 1];
            w2 += p * c_gate[g * 4 + 2];
            w3 += p * c_gate[g * 4 + 3];
        }
        reinterpret_cast<float4*>(w)[t] = make_float4(w0, w1, w2, w3);
    }
}

// Main kernel: 4 consecutive pixels (one row segment) per thread.
// grid = (3, OUT_CH, NB), block = 192 (576 threads per (b,o) pair).
// Leaf offsets are wave-uniform scalars; no bounds checks (padded input).
__global__ __launch_bounds__(192) void ltc_kernel(
    const float* __restrict__ xp,       // [B][64][50][50]
    const int*   __restrict__ leaf_idx, // [OUT_CH][8]
    const float* __restrict__ w,        // [OUT_CH][7][4]
    float*       __restrict__ out)      // [B][OUT_CH][48][48]
{
    const int t  = blockIdx.x * 192 + threadIdx.x;   // 0..575
    const int o  = blockIdx.y;
    const int b  = blockIdx.z;
    const int p0 = t * 4;                            // multiple of 4; 48%4==0
    const int ph = p0 / NW;
    const int pw = p0 - ph * NW;
    const int lane_off = ph * PW + pw;               // top-left of 3x3 window in xp

    const float* xb = xp + (size_t)b * IN_CH * PPIX;

    // load 28 node weights (wave-uniform -> scalar regs)
    const float* wo = w + (size_t)o * NUM_NODES * 4;
    float wv[NUM_NODES][4];
#pragma unroll
    for (int n = 0; n < NUM_NODES; ++n) {
#pragma unroll
        for (int q = 0; q < 4; ++q) wv[n][q] = wo[n * 4 + q];
    }

    // gather 8 leaves x 4 pixels
    float v[NUM_LEAVES][4];
#pragma unroll
    for (int l = 0; l < NUM_LEAVES; ++l) {
        int idx = leaf_idx[o * NUM_LEAVES + l];   // wave-uniform
        int c  = idx / 9;
        int k  = idx - c * 9;
        int di = k / 3;                            // 0..2
        int dj = k - di * 3;                       // 0..2
        const float* s = xb + c * PPIX + di * PW + dj + lane_off;
        v[l][0] = s[0]; v[l][1] = s[1]; v[l][2] = s[2]; v[l][3] = s[3];
    }

    float4 res;
    float* rp = &res.x;
#pragma unroll
    for (int j = 0; j < 4; ++j) {
        float tn[4];
#pragma unroll
        for (int n = 0; n < 4; ++n) {
            float a  = v[2 * n][j];
            float bb = v[2 * n + 1][j];
            tn[n] = wv[n][0] + wv[n][1] * a + wv[n][2] * bb + wv[n][3] * (a * bb);
        }
        float u0 = wv[4][0] + wv[4][1] * tn[0] + wv[4][2] * tn[1] + wv[4][3] * (tn[0] * tn[1]);
        float u1 = wv[5][0] + wv[5][1] * tn[2] + wv[5][2] * tn[3] + wv[5][3] * (tn[2] * tn[3]);
        rp[j]    = wv[6][0] + wv[6][1] * u0 + wv[6][2] * u1 + wv[6][3] * (u0 * u1);
    }

    *reinterpret_cast<float4*>(out + ((size_t)(b * OUT_CH + o)) * NPIX + p0) = res;
}

extern "C" void kernel_launch(void* const* d_in, const int* in_sizes, int n_in,
                              void* d_out, int out_size, void* d_ws, size_t ws_size,
                              hipStream_t stream) {
    const float* x        = (const float*)d_in[0];
    const float* logits   = (const float*)d_in[1];
    const int*   leaf_idx = (const int*)d_in[2];
    float*       out      = (float*)d_out;

    float* w  = (float*)d_ws;                                  // 28,672 B
    float* xp = (float*)((char*)d_ws + 32768);                 // 10,240,000 B

    // 1) fused pad + weight precompute
    prep_kernel<<<PAD_BLOCKS + W_BLOCKS, 256, 0, stream>>>(x, logits, xp, w);

    // 2) main compute
    dim3 grid(3, OUT_CH, NB);
    ltc_kernel<<<grid, 192, 0, stream>>>(xp, leaf_idx, w, out);
}